// Round 8
// baseline (220.309 us; speedup 1.0000x reference)
//
#include <hip/hip_runtime.h>

#define B_ 64
#define N_ 768
#define F_ 256
#define P_ 64
#define T_ 16
#define K_ 3
#define L_ 12
#define CH_ 3          // column chunks per (b,l)
#define CCOL 256       // cols per chunk
#define TSTR 260       // tmp row stride (dwords); ==4 mod 32 banks, 16B-aligned

#define ADJ_BLOCKS (B_ * L_ * CH_)   // 2304
#define CONV_BLOCKS (B_ * L_ / 4)    // 192 (4 waves each, 1 wave per (b,l))
// grid = 2496 = 192*13; conv role at blk%13==0, adj otherwise (interleaved).

__global__ __launch_bounds__(256, 5) void fused_pool_kernel(
    const float* __restrict__ x, const float* __restrict__ adj,
    const float* __restrict__ conv_w, const float* __restrict__ conv_b,
    const float* __restrict__ re_param,
    float* __restrict__ out_x, float* __restrict__ out_adj)
{
    __shared__ float sT[P_][T_];     // 4 KB: sT[p][t] = s[t,p]
    __shared__ float tmp[T_][TSTR];  // 16.25 KB

    const int blk  = blockIdx.x;
    const int tid  = threadIdx.x;
    const int w    = tid >> 6;
    const int lane = tid & 63;

    if (blk % 13 == 0) {
        // ================= conv role: 1 wave per (b,l), lane owns 4 f-cols =================
        const int widx = (blk / 13) * 4 + w;          // 0..767
        const int b = widx / L_, l = widx % L_;
        const float* xb = x + (size_t)b * N_ * F_ + (size_t)l * F_ + 4 * lane;

        float acc[T_][4];
        #pragma unroll
        for (int t = 0; t < T_; ++t) {
            const float bv = conv_b[t];
            acc[t][0] = bv; acc[t][1] = bv; acc[t][2] = bv; acc[t][3] = bv;
        }

        float4 cbA[2], cbB[2];
        auto loadC = [&](float4* buf, int p0) {
            #pragma unroll
            for (int r = 0; r < 2; ++r)
                buf[r] = *(const float4*)(xb + (size_t)(p0 + r) * (L_ * F_));
        };
        auto compC = [&](const float4* buf, int p0) {
            #pragma unroll
            for (int r = 0; r < 2; ++r) {
                const float4 v = buf[r];
                float lf = __shfl_up(v.w, 1, 64);
                float rt = __shfl_down(v.x, 1, 64);
                if (lane == 0)  lf = 0.f;   // f == 0 boundary
                if (lane == 63) rt = 0.f;   // f == 255 boundary
                const float* wp = conv_w + (p0 + r) * K_;   // uniform -> s_load
                #pragma unroll
                for (int t = 0; t < T_; ++t) {
                    const float w0 = wp[t * (P_ * K_) + 0];
                    const float w1 = wp[t * (P_ * K_) + 1];
                    const float w2 = wp[t * (P_ * K_) + 2];
                    acc[t][0] = fmaf(lf,  w0, fmaf(v.x, w1, fmaf(v.y, w2, acc[t][0])));
                    acc[t][1] = fmaf(v.x, w0, fmaf(v.y, w1, fmaf(v.z, w2, acc[t][1])));
                    acc[t][2] = fmaf(v.y, w0, fmaf(v.z, w1, fmaf(v.w, w2, acc[t][2])));
                    acc[t][3] = fmaf(v.z, w0, fmaf(v.w, w1, fmaf(rt,  w2, acc[t][3])));
                }
            }
        };

        loadC(cbA, 0);
        for (int it = 0; it < 16; ++it) {        // dynamic: keep I-cache small
            const int p0 = it * 4;
            loadC(cbB, p0 + 2);
            compC(cbA, p0);
            if (it < 15) loadC(cbA, p0 + 4);
            compC(cbB, p0 + 2);
        }

        float* ob = out_x + (size_t)b * (T_ * L_) * F_ + 4 * lane;
        #pragma unroll
        for (int t = 0; t < T_; ++t) {
            float4 v;
            v.x = acc[t][0]; v.y = acc[t][1]; v.z = acc[t][2]; v.w = acc[t][3];
            *(float4*)(ob + (size_t)(t * L_ + l) * F_) = v;
        }
        return;
    }

    // ================= adj role: one (b,l,chunk) =================
    const int aidx = blk - blk / 13 - 1;          // 0..2303 (bijective over blk%13!=0)
    const int bl = aidx / CH_, c = aidx % CH_;
    const int b = bl / L_, l = bl % L_;

    // s[t,p] = sum_k conv_w[t,p,k] * re_param[k]
    const float r0 = re_param[0], r1 = re_param[1], r2 = re_param[2];
    for (int i = tid; i < P_ * T_; i += 256) {
        const int p = i >> 4, t = i & 15;
        const float* wv = conv_w + (size_t)t * (P_ * K_) + (size_t)p * K_;
        sT[p][t] = wv[0] * r0 + wv[1] * r1 + wv[2] * r2;
    }
    __syncthreads();

    // Phase A: tmp[4w+j][4*lane+e] = sum_p sT[p][4w+j] * adj[row p][chunk col]
    // 4-row batches, double-buffered: 8 x 1KiB wave-loads in flight.
    float acc[4][4];
    #pragma unroll
    for (int j = 0; j < 4; ++j) {
        acc[j][0] = 0.f; acc[j][1] = 0.f; acc[j][2] = 0.f; acc[j][3] = 0.f;
    }

    const float* ab = adj + (size_t)bl * (P_ * N_) + c * CCOL + 4 * lane;
    float4 bA[4], bB[4];
    auto loadA = [&](float4* buf, int p0) {
        #pragma unroll
        for (int r = 0; r < 4; ++r)
            buf[r] = *(const float4*)(ab + (size_t)(p0 + r) * N_);
    };
    auto compA = [&](const float4* buf, int p0) {
        #pragma unroll
        for (int r = 0; r < 4; ++r) {
            const float4 sv = *(const float4*)&sT[p0 + r][4 * w];  // uniform b128 broadcast
            const float4 a = buf[r];
            acc[0][0] = fmaf(sv.x, a.x, acc[0][0]);
            acc[0][1] = fmaf(sv.x, a.y, acc[0][1]);
            acc[0][2] = fmaf(sv.x, a.z, acc[0][2]);
            acc[0][3] = fmaf(sv.x, a.w, acc[0][3]);
            acc[1][0] = fmaf(sv.y, a.x, acc[1][0]);
            acc[1][1] = fmaf(sv.y, a.y, acc[1][1]);
            acc[1][2] = fmaf(sv.y, a.z, acc[1][2]);
            acc[1][3] = fmaf(sv.y, a.w, acc[1][3]);
            acc[2][0] = fmaf(sv.z, a.x, acc[2][0]);
            acc[2][1] = fmaf(sv.z, a.y, acc[2][1]);
            acc[2][2] = fmaf(sv.z, a.z, acc[2][2]);
            acc[2][3] = fmaf(sv.z, a.w, acc[2][3]);
            acc[3][0] = fmaf(sv.w, a.x, acc[3][0]);
            acc[3][1] = fmaf(sv.w, a.y, acc[3][1]);
            acc[3][2] = fmaf(sv.w, a.z, acc[3][2]);
            acc[3][3] = fmaf(sv.w, a.w, acc[3][3]);
        }
    };

    loadA(bA, 0);
    #pragma unroll
    for (int it = 0; it < 8; ++it) {
        const int p0 = it * 8;
        loadA(bB, p0 + 4);
        compA(bA, p0);
        if (it < 7) loadA(bA, p0 + 8);
        compA(bB, p0 + 4);
    }

    #pragma unroll
    for (int j = 0; j < 4; ++j) {
        float4 v;
        v.x = acc[j][0]; v.y = acc[j][1]; v.z = acc[j][2]; v.w = acc[j][3];
        *(float4*)&tmp[4 * w + j][4 * lane] = v;
    }
    __syncthreads();

    // Phase B: out[b, l*T+t, (4c+mi)*T+u] = sum_q tmp[t][mi*64+q] * sT[q][u]
    const int t = tid >> 4, u = tid & 15;
    float sum[4] = {0.f, 0.f, 0.f, 0.f};

    for (int q4 = 0; q4 < P_; q4 += 4) {
        const float s0 = sT[q4 + 0][u];
        const float s1 = sT[q4 + 1][u];
        const float s2 = sT[q4 + 2][u];
        const float s3 = sT[q4 + 3][u];
        #pragma unroll
        for (int mi = 0; mi < 4; ++mi) {
            const float4 tv = *(const float4*)&tmp[t][mi * P_ + q4];  // 16-lane broadcast
            sum[mi] = fmaf(tv.x, s0, fmaf(tv.y, s1, fmaf(tv.z, s2, fmaf(tv.w, s3, sum[mi]))));
        }
    }

    float* ob = out_adj + (size_t)b * (L_ * T_) * (L_ * T_)
                        + (size_t)(l * T_ + t) * (L_ * T_)
                        + (size_t)(4 * c) * T_ + u;
    #pragma unroll
    for (int mi = 0; mi < 4; ++mi)
        ob[mi * T_] = sum[mi];
}

// ---------------------------------------------------------------------------
extern "C" void kernel_launch(void* const* d_in, const int* in_sizes, int n_in,
                              void* d_out, int out_size, void* d_ws, size_t ws_size,
                              hipStream_t stream) {
    (void)in_sizes; (void)n_in; (void)out_size; (void)d_ws; (void)ws_size;
    const float* x        = (const float*)d_in[0];
    const float* adj      = (const float*)d_in[1];
    const float* conv_w   = (const float*)d_in[2];
    const float* conv_b   = (const float*)d_in[3];
    const float* re_param = (const float*)d_in[4];

    float* pooled_x   = (float*)d_out;
    float* pooled_adj = (float*)d_out + (size_t)B_ * (T_ * L_) * F_;

    fused_pool_kernel<<<ADJ_BLOCKS + CONV_BLOCKS, 256, 0, stream>>>(
        x, adj, conv_w, conv_b, re_param, pooled_x, pooled_adj);
}

// Round 9
// 127.187 us; speedup vs baseline: 1.7322x; 1.7322x over previous
//
#include <hip/hip_runtime.h>

#define B_ 64
#define N_ 768
#define F_ 256
#define P_ 64
#define T_ 16
#define K_ 3
#define L_ 12
#define CH_ 3          // column chunks per (b,l)
#define CCOL 256       // cols per chunk
#define TSTR 260       // tmp row stride (dwords); ==4 mod 32 banks, 16B-aligned

// grid = 3072 blocks of 256 threads, groups of 4: 3 adj-chunk blocks + 1 conv block.
//   blk&3 == 3 : conv role, idx = blk>>2 (768 blocks)
//   else       : adj role, aidx = 3*(blk>>2) + (blk&3) (2304 blocks)
// adj role: wave w owns t=4w..4w+3; each wave streams its 64x256 chunk with a
// register ping-pong (two 4-row float4 buffers -> 4-8 KB/wave in flight).
// LDS 20.7 KB -> 7 blocks/CU; VGPR capped 85 -> no spill at ~70 live.
__global__ __launch_bounds__(256, 6) void fused_pool_kernel(
    const float* __restrict__ x, const float* __restrict__ adj,
    const float* __restrict__ conv_w, const float* __restrict__ conv_b,
    const float* __restrict__ re_param,
    float* __restrict__ out_x, float* __restrict__ out_adj)
{
    __shared__ float sT[P_][T_];     // 4 KB: sT[p][t] = s[t,p]
    __shared__ float tmp[T_][TSTR];  // 16.25 KB

    const int blk = blockIdx.x;
    const int tid = threadIdx.x;

    if ((blk & 3) == 3) {
        // ================= conv role (R2's proven path) =================
        const int idx = blk >> 2;
        const int b = idx / L_, l = idx % L_;
        const int f = tid;
        const float* xb = x + (size_t)b * N_ * F_ + (size_t)l * F_;

        float acc[T_];
        #pragma unroll
        for (int t = 0; t < T_; ++t) acc[t] = conv_b[t];

        for (int p = 0; p < P_; ++p) {
            const float* row = xb + (size_t)p * (L_ * F_);
            const float xm = (f > 0)      ? row[f - 1] : 0.f;
            const float x0 = row[f];
            const float xp = (f < F_ - 1) ? row[f + 1] : 0.f;
            const float* wp = conv_w + p * K_;   // thread-uniform -> s_load
            #pragma unroll
            for (int t = 0; t < T_; ++t) {
                acc[t] = fmaf(xm, wp[t * (P_ * K_)],
                         fmaf(x0, wp[t * (P_ * K_) + 1],
                         fmaf(xp, wp[t * (P_ * K_) + 2], acc[t])));
            }
        }
        float* ob = out_x + (size_t)b * (T_ * L_) * F_ + f;
        #pragma unroll
        for (int t = 0; t < T_; ++t)
            ob[(size_t)(t * L_ + l) * F_] = acc[t];
        return;
    }

    // ================= adj role: one (b,l,chunk) =================
    const int aidx = 3 * (blk >> 2) + (blk & 3);   // 0..2303
    const int bl = aidx / CH_, c = aidx % CH_;
    const int b = bl / L_, l = bl % L_;
    const int w    = tid >> 6;
    const int lane = tid & 63;

    // s[t,p] = sum_k conv_w[t,p,k] * re_param[k]
    const float r0 = re_param[0], r1 = re_param[1], r2 = re_param[2];
    for (int i = tid; i < P_ * T_; i += 256) {
        const int p = i >> 4, t = i & 15;
        const float* wv = conv_w + (size_t)t * (P_ * K_) + (size_t)p * K_;
        sT[p][t] = wv[0] * r0 + wv[1] * r1 + wv[2] * r2;
    }
    __syncthreads();

    // Phase A: acc[j][e] = sum_p sT[p][4w+j] * adj[row p][4*lane+e of chunk c]
    float acc[4][4];
    #pragma unroll
    for (int j = 0; j < 4; ++j) {
        acc[j][0] = 0.f; acc[j][1] = 0.f; acc[j][2] = 0.f; acc[j][3] = 0.f;
    }

    const float* ab = adj + (size_t)bl * (P_ * N_) + c * CCOL + 4 * lane;

#define LD(P) (*(const float4*)(ab + (size_t)(P) * N_))
#define FMA16(V, P) do {                                          \
        const float4 sv_ = *(const float4*)&sT[(P)][4 * w];       \
        acc[0][0] = fmaf(sv_.x, (V).x, acc[0][0]);                \
        acc[0][1] = fmaf(sv_.x, (V).y, acc[0][1]);                \
        acc[0][2] = fmaf(sv_.x, (V).z, acc[0][2]);                \
        acc[0][3] = fmaf(sv_.x, (V).w, acc[0][3]);                \
        acc[1][0] = fmaf(sv_.y, (V).x, acc[1][0]);                \
        acc[1][1] = fmaf(sv_.y, (V).y, acc[1][1]);                \
        acc[1][2] = fmaf(sv_.y, (V).z, acc[1][2]);                \
        acc[1][3] = fmaf(sv_.y, (V).w, acc[1][3]);                \
        acc[2][0] = fmaf(sv_.z, (V).x, acc[2][0]);                \
        acc[2][1] = fmaf(sv_.z, (V).y, acc[2][1]);                \
        acc[2][2] = fmaf(sv_.z, (V).z, acc[2][2]);                \
        acc[2][3] = fmaf(sv_.z, (V).w, acc[2][3]);                \
        acc[3][0] = fmaf(sv_.w, (V).x, acc[3][0]);                \
        acc[3][1] = fmaf(sv_.w, (V).y, acc[3][1]);                \
        acc[3][2] = fmaf(sv_.w, (V).z, acc[3][2]);                \
        acc[3][3] = fmaf(sv_.w, (V).w, acc[3][3]);                \
    } while (0)

    // register ping-pong: named buffers, never address-taken
    float4 A0 = LD(0), A1 = LD(1), A2 = LD(2), A3 = LD(3);
    float4 B0 = LD(4), B1 = LD(5), B2 = LD(6), B3 = LD(7);

    #pragma unroll
    for (int i = 0; i < 8; ++i) {
        const int p0 = 8 * i;
        FMA16(A0, p0 + 0); FMA16(A1, p0 + 1);
        FMA16(A2, p0 + 2); FMA16(A3, p0 + 3);
        if (i < 7) {
            A0 = LD(p0 + 8);  A1 = LD(p0 + 9);
            A2 = LD(p0 + 10); A3 = LD(p0 + 11);
        }
        FMA16(B0, p0 + 4); FMA16(B1, p0 + 5);
        FMA16(B2, p0 + 6); FMA16(B3, p0 + 7);
        if (i < 7) {
            B0 = LD(p0 + 12); B1 = LD(p0 + 13);
            B2 = LD(p0 + 14); B3 = LD(p0 + 15);
        }
    }
#undef LD
#undef FMA16

    #pragma unroll
    for (int j = 0; j < 4; ++j) {
        float4 v;
        v.x = acc[j][0]; v.y = acc[j][1]; v.z = acc[j][2]; v.w = acc[j][3];
        *(float4*)&tmp[4 * w + j][4 * lane] = v;   // sequential 16B per lane
    }
    __syncthreads();

    // Phase B: out[b, l*T+t, (4c+mi)*T+u] = sum_q tmp[t][mi*64+q] * sT[q][u]
    const int t = tid >> 4, u = tid & 15;
    float sum[4] = {0.f, 0.f, 0.f, 0.f};

    for (int q4 = 0; q4 < P_; q4 += 4) {
        const float s0 = sT[q4 + 0][u];
        const float s1 = sT[q4 + 1][u];
        const float s2 = sT[q4 + 2][u];
        const float s3 = sT[q4 + 3][u];
        #pragma unroll
        for (int mi = 0; mi < 4; ++mi) {
            const float4 tv = *(const float4*)&tmp[t][mi * P_ + q4];  // broadcast
            sum[mi] = fmaf(tv.x, s0, fmaf(tv.y, s1, fmaf(tv.z, s2, fmaf(tv.w, s3, sum[mi]))));
        }
    }

    float* ob = out_adj + (size_t)b * (L_ * T_) * (L_ * T_)
                        + (size_t)(l * T_ + t) * (L_ * T_)
                        + (size_t)(4 * c) * T_ + u;
    #pragma unroll
    for (int mi = 0; mi < 4; ++mi)
        ob[mi * T_] = sum[mi];
}

// ---------------------------------------------------------------------------
extern "C" void kernel_launch(void* const* d_in, const int* in_sizes, int n_in,
                              void* d_out, int out_size, void* d_ws, size_t ws_size,
                              hipStream_t stream) {
    (void)in_sizes; (void)n_in; (void)out_size; (void)d_ws; (void)ws_size;
    const float* x        = (const float*)d_in[0];
    const float* adj      = (const float*)d_in[1];
    const float* conv_w   = (const float*)d_in[2];
    const float* conv_b   = (const float*)d_in[3];
    const float* re_param = (const float*)d_in[4];

    float* pooled_x   = (float*)d_out;
    float* pooled_adj = (float*)d_out + (size_t)B_ * (T_ * L_) * F_;

    fused_pool_kernel<<<B_ * L_ * 4, 256, 0, stream>>>(
        x, adj, conv_w, conv_b, re_param, pooled_x, pooled_adj);
}

// Round 10
// 110.346 us; speedup vs baseline: 1.9965x; 1.1526x over previous
//
#include <hip/hip_runtime.h>

#define B_ 64
#define N_ 768
#define F_ 256
#define P_ 64
#define T_ 16
#define K_ 3
#define L_ 12
#define CH_ 3          // column chunks per (b,l)
#define CCOL 256       // cols per chunk
#define TSTR 260       // tmp row stride (dwords); ==4 mod 32 banks, 16B-aligned

// grid = 3072 blocks of 256 threads, groups of 4: 3 adj-chunk blocks + 1 conv.
//   blk&3 == 3 : conv role, idx = blk>>2 (768 blocks)
//   else       : adj role, aidx = 3*(blk>>2) + (blk&3) (2304 blocks)
// adj role: wave w owns t=4w..4w+3. p-loop is DYNAMIC (unroll 1) with a
// pointer-bump base: no address hoisting -> no spill (the R8/R9 failure).
// 8 named float4 rows per iteration = 8 KiB/wave in flight per burst.
__global__ __launch_bounds__(256, 6) void fused_pool_kernel(
    const float* __restrict__ x, const float* __restrict__ adj,
    const float* __restrict__ conv_w, const float* __restrict__ conv_b,
    const float* __restrict__ re_param,
    float* __restrict__ out_x, float* __restrict__ out_adj)
{
    __shared__ float sT[P_][T_];     // 4 KB: sT[p][t] = s[t,p]
    __shared__ float tmp[T_][TSTR];  // 16.25 KB  (total 20.7 KB -> 7 blocks/CU)

    const int blk = blockIdx.x;
    const int tid = threadIdx.x;

    if ((blk & 3) == 3) {
        // ================= conv role (proven lean path) =================
        const int idx = blk >> 2;
        const int b = idx / L_, l = idx % L_;
        const int f = tid;
        const float* xb = x + (size_t)b * N_ * F_ + (size_t)l * F_;

        float acc[T_];
        #pragma unroll
        for (int t = 0; t < T_; ++t) acc[t] = conv_b[t];

        #pragma unroll 1
        for (int p = 0; p < P_; ++p) {
            const float* row = xb + (size_t)p * (L_ * F_);
            const float xm = (f > 0)      ? row[f - 1] : 0.f;
            const float x0 = row[f];
            const float xp = (f < F_ - 1) ? row[f + 1] : 0.f;
            const float* wp = conv_w + p * K_;   // thread-uniform -> s_load
            #pragma unroll
            for (int t = 0; t < T_; ++t) {
                acc[t] = fmaf(xm, wp[t * (P_ * K_)],
                         fmaf(x0, wp[t * (P_ * K_) + 1],
                         fmaf(xp, wp[t * (P_ * K_) + 2], acc[t])));
            }
        }
        float* ob = out_x + (size_t)b * (T_ * L_) * F_ + f;
        #pragma unroll
        for (int t = 0; t < T_; ++t)
            ob[(size_t)(t * L_ + l) * F_] = acc[t];
        return;
    }

    // ================= adj role: one (b,l,chunk) =================
    const int aidx = 3 * (blk >> 2) + (blk & 3);   // 0..2303
    const int bl = aidx / CH_, c = aidx % CH_;
    const int b = bl / L_, l = bl % L_;
    const int w    = tid >> 6;
    const int lane = tid & 63;

    // s[t,p] = sum_k conv_w[t,p,k] * re_param[k]
    const float r0 = re_param[0], r1 = re_param[1], r2 = re_param[2];
    for (int i = tid; i < P_ * T_; i += 256) {
        const int p = i >> 4, t = i & 15;
        const float* wv = conv_w + (size_t)t * (P_ * K_) + (size_t)p * K_;
        sT[p][t] = wv[0] * r0 + wv[1] * r1 + wv[2] * r2;
    }
    __syncthreads();

    // Phase A: acc[j][e] = sum_p sT[p][4w+j] * adj[row p][4*lane+e of chunk c]
    float acc[4][4];
    #pragma unroll
    for (int j = 0; j < 4; ++j) {
        acc[j][0] = 0.f; acc[j][1] = 0.f; acc[j][2] = 0.f; acc[j][3] = 0.f;
    }

    const float* ap = adj + (size_t)bl * (P_ * N_) + c * CCOL + 4 * lane;
    const float* sp = &sT[0][4 * w];

#define FMA16(V, SPTR) do {                                       \
        const float4 sv_ = *(const float4*)(SPTR);                \
        acc[0][0] = fmaf(sv_.x, (V).x, acc[0][0]);                \
        acc[0][1] = fmaf(sv_.x, (V).y, acc[0][1]);                \
        acc[0][2] = fmaf(sv_.x, (V).z, acc[0][2]);                \
        acc[0][3] = fmaf(sv_.x, (V).w, acc[0][3]);                \
        acc[1][0] = fmaf(sv_.y, (V).x, acc[1][0]);                \
        acc[1][1] = fmaf(sv_.y, (V).y, acc[1][1]);                \
        acc[1][2] = fmaf(sv_.y, (V).z, acc[1][2]);                \
        acc[1][3] = fmaf(sv_.y, (V).w, acc[1][3]);                \
        acc[2][0] = fmaf(sv_.z, (V).x, acc[2][0]);                \
        acc[2][1] = fmaf(sv_.z, (V).y, acc[2][1]);                \
        acc[2][2] = fmaf(sv_.z, (V).z, acc[2][2]);                \
        acc[2][3] = fmaf(sv_.z, (V).w, acc[2][3]);                \
        acc[3][0] = fmaf(sv_.w, (V).x, acc[3][0]);                \
        acc[3][1] = fmaf(sv_.w, (V).y, acc[3][1]);                \
        acc[3][2] = fmaf(sv_.w, (V).z, acc[3][2]);                \
        acc[3][3] = fmaf(sv_.w, (V).w, acc[3][3]);                \
    } while (0)

    #pragma unroll 1
    for (int it = 0; it < 8; ++it) {
        // 8-row burst: named regs, addresses from one bumped base only
        const float4 a0 = *(const float4*)(ap + 0 * (size_t)N_);
        const float4 a1 = *(const float4*)(ap + 1 * (size_t)N_);
        const float4 a2 = *(const float4*)(ap + 2 * (size_t)N_);
        const float4 a3 = *(const float4*)(ap + 3 * (size_t)N_);
        const float4 a4 = *(const float4*)(ap + 4 * (size_t)N_);
        const float4 a5 = *(const float4*)(ap + 5 * (size_t)N_);
        const float4 a6 = *(const float4*)(ap + 6 * (size_t)N_);
        const float4 a7 = *(const float4*)(ap + 7 * (size_t)N_);
        FMA16(a0, sp + 0 * T_);
        FMA16(a1, sp + 1 * T_);
        FMA16(a2, sp + 2 * T_);
        FMA16(a3, sp + 3 * T_);
        FMA16(a4, sp + 4 * T_);
        FMA16(a5, sp + 5 * T_);
        FMA16(a6, sp + 6 * T_);
        FMA16(a7, sp + 7 * T_);
        ap += 8 * (size_t)N_;
        sp += 8 * T_;
    }
#undef FMA16

    #pragma unroll
    for (int j = 0; j < 4; ++j) {
        float4 v;
        v.x = acc[j][0]; v.y = acc[j][1]; v.z = acc[j][2]; v.w = acc[j][3];
        *(float4*)&tmp[4 * w + j][4 * lane] = v;   // sequential 16B per lane
    }
    __syncthreads();

    // Phase B: out[b, l*T+t, (4c+mi)*T+u] = sum_q tmp[t][mi*64+q] * sT[q][u]
    const int t = tid >> 4, u = tid & 15;
    float sum[4] = {0.f, 0.f, 0.f, 0.f};

    #pragma unroll 1
    for (int q4 = 0; q4 < P_; q4 += 4) {
        const float s0 = sT[q4 + 0][u];
        const float s1 = sT[q4 + 1][u];
        const float s2 = sT[q4 + 2][u];
        const float s3 = sT[q4 + 3][u];
        #pragma unroll
        for (int mi = 0; mi < 4; ++mi) {
            const float4 tv = *(const float4*)&tmp[t][mi * P_ + q4];  // broadcast
            sum[mi] = fmaf(tv.x, s0, fmaf(tv.y, s1, fmaf(tv.z, s2, fmaf(tv.w, s3, sum[mi]))));
        }
    }

    float* ob = out_adj + (size_t)b * (L_ * T_) * (L_ * T_)
                        + (size_t)(l * T_ + t) * (L_ * T_)
                        + (size_t)(4 * c) * T_ + u;
    #pragma unroll
    for (int mi = 0; mi < 4; ++mi)
        ob[mi * T_] = sum[mi];
}

// ---------------------------------------------------------------------------
extern "C" void kernel_launch(void* const* d_in, const int* in_sizes, int n_in,
                              void* d_out, int out_size, void* d_ws, size_t ws_size,
                              hipStream_t stream) {
    (void)in_sizes; (void)n_in; (void)out_size; (void)d_ws; (void)ws_size;
    const float* x        = (const float*)d_in[0];
    const float* adj      = (const float*)d_in[1];
    const float* conv_w   = (const float*)d_in[2];
    const float* conv_b   = (const float*)d_in[3];
    const float* re_param = (const float*)d_in[4];

    float* pooled_x   = (float*)d_out;
    float* pooled_adj = (float*)d_out + (size_t)B_ * (T_ * L_) * F_;

    fused_pool_kernel<<<B_ * L_ * 4, 256, 0, stream>>>(
        x, adj, conv_w, conv_b, re_param, pooled_x, pooled_adj);
}